// Round 3
// baseline (1057.526 us; speedup 1.0000x reference)
//
#include <hip/hip_runtime.h>
#include <cstdint>
#include <cstddef>

// ExpertGather: Y[b,e,k,j] = sum_i X[b, ind[b,e,k], i] * W[e,i,j]
// B=4 T=4096 I=1024 E=16 K=512 J=1024
// Round 6: r4's phase schedule (best measured) + 2 blocks/CU.
//  - Phase = K-half (32 halves total): 12 ds_read_b128 (bf read once/phase),
//    stage B(u+1) then A(u+2), barrier, lgkmcnt(0)+sched_barrier (r4's proven
//    discipline; r5 showed compiler-scheduled waits are worse), setprio(1),
//    32 MFMA, setprio(0), vmcnt(2) counted (never 0 until tail), barrier.
//  - Asymmetric ring fits 80KB/block -> 2 blocks/CU (the TLP r4 lacked):
//    A = 3x16KB units (lookahead 2), B = 2x16KB (lookahead 1). Issue order
//    B-before-A makes vmcnt(2) drain exactly {A(u+1),B(u+1)} each phase.
//  - rowid/is64 aliased into ring LDS before the main loop (no extra LDS);
//    smem = 81920 B exactly -> 2x81920 = 160KB/CU.
//  - Swizzle, staging math, MFMA layout, epilogue: verbatim from r4/r5
//    (verified). Numeric accumulation order unchanged.

typedef float    floatx4 __attribute__((ext_vector_type(4)));
typedef _Float16 half8   __attribute__((ext_vector_type(8)));

constexpr int Bc = 4, Tc = 4096, Ic = 1024, Ec = 16, Kc = 512, Jc = 1024;
constexpr int BM = 256, BN = 256, NT = 512;
constexpr int UNIT = 16384;          // one K-half unit: 256 rows x 32 halves x 2B
constexpr int A_RING = 3 * UNIT;     // 49152
constexpr int SMEM_BYTES = A_RING + 2 * UNIT;  // 81920 exactly

__device__ __forceinline__ void async16(const void* g, void* l) {
  __builtin_amdgcn_global_load_lds(
      (const __attribute__((address_space(1))) uint32_t*)g,
      (__attribute__((address_space(3))) uint32_t*)l, 16, 0, 0);
}

// ---------- fused pre-pass: W transpose->fp16 (blocks 0..4095), X->fp16 (rest) ----------
__global__ void cvt_kernel(const float* __restrict__ X, _Float16* __restrict__ Xh, int n8,
                           const float* __restrict__ W, _Float16* __restrict__ WT) {
  __shared__ float tile[64][65];
  const int bidx = blockIdx.x;
  if (bidx >= Ec * 256) {
    int i = (bidx - Ec * 256) * blockDim.x + threadIdx.x;
    const int stride = 2048 * blockDim.x;
    for (; i < n8; i += stride) {
      floatx4 v0 = ((const floatx4*)X)[2 * i];
      floatx4 v1 = ((const floatx4*)X)[2 * i + 1];
      half8 h;
      h[0] = (_Float16)v0.x; h[1] = (_Float16)v0.y; h[2] = (_Float16)v0.z; h[3] = (_Float16)v0.w;
      h[4] = (_Float16)v1.x; h[5] = (_Float16)v1.y; h[6] = (_Float16)v1.z; h[7] = (_Float16)v1.w;
      ((half8*)Xh)[i] = h;
    }
    return;
  }
  const int bid = bidx;
  const int e  = bid >> 8;
  const int i0 = ((bid >> 4) & 15) * 64;
  const int j0 = (bid & 15) * 64;
  const int tid = threadIdx.x;
  const int r  = tid >> 4;
  const int c4 = tid & 15;
  const float* src = W + ((size_t)e << 20) + (size_t)i0 * Jc + j0;
#pragma unroll
  for (int s = 0; s < 4; s++) {
    int rr = r + s * 16;
    floatx4 v = *(const floatx4*)(src + (size_t)rr * Jc + c4 * 4);
    tile[rr][c4 * 4 + 0] = v.x; tile[rr][c4 * 4 + 1] = v.y;
    tile[rr][c4 * 4 + 2] = v.z; tile[rr][c4 * 4 + 3] = v.w;
  }
  __syncthreads();
  const int jj = tid >> 2;
  const int ig = tid & 3;
  half8 hv0, hv1;
#pragma unroll
  for (int q = 0; q < 8; q++) hv0[q] = (_Float16)tile[ig * 16 + q][jj];
#pragma unroll
  for (int q = 0; q < 8; q++) hv1[q] = (_Float16)tile[ig * 16 + 8 + q][jj];
  _Float16* dst = WT + ((size_t)e << 20) + (size_t)(j0 + jj) * Ic + i0 + ig * 16;
  ((half8*)dst)[0] = hv0;
  ((half8*)dst)[1] = hv1;
}

// ---------- main grouped GEMM ----------
// Grid 512 = 8 chunks x 8 sharers x 8 XCD-slots (unchanged, verified).
// MFMA layouts (m89-verified): A/B m(n)=lane&15, k=(lane>>4)*8+j;
// C/D col=lane&15, row=(lane>>4)*4+reg.
__global__ __launch_bounds__(NT, 4) void gemm_kernel(
    const int* __restrict__ ind32,
    const _Float16* __restrict__ Xh, const _Float16* __restrict__ WT,
    float* __restrict__ Y) {
  __shared__ alignas(16) unsigned char smem[SMEM_BYTES];  // 80 KB exactly
  char* smemc = (char*)smem;
  int* itmp = (int*)smem;      // rowid[0..255], is64 flag at [256] (pre-loop alias)
  float* lbuf = (float*)smem;  // epilogue reuse (32x257 floats fits)

  const int tid = threadIdx.x;
  const int bid = blockIdx.x;
  const int x = bid & 7, s = (bid >> 3) & 7, chunk = bid >> 6;
  const int g = chunk * 8 + x;       // 0..63 B-tile group
  const int e = g >> 2, nt = g & 3;  // expert, j-tile
  const int b = s >> 1, mt = s & 1;  // batch, k-tile
  const int be = b * Ec + e;
  const int k0 = mt * BM;
  const int j0 = nt * BN;

  // index dtype probe (int64 vs int32 storage), wave-parallel
  if (tid < 64) {
    int v = ind32[2 * tid + 1];
    unsigned long long m = __ballot(v != 0);
    if (tid == 0) itmp[256] = (m == 0ULL) ? 1 : 0;
  }
  __syncthreads();
  const int is64 = itmp[256];
  if (tid < BM) {
    int idx = be * Kc + k0 + tid;
    itmp[tid] = is64 ? ind32[2 * idx] : ind32[idx];
  }
  __syncthreads();

  const int lane = tid & 63;
  const int wave = tid >> 6;           // 0..7
  const int wmb = (wave >> 2) * 128;   // wave m base (2 rows of waves)
  const int wnb = (wave & 3) * 64;     // wave n base (4 cols of waves)
  const int quad = lane >> 4;
  const int tr = lane & 15;

  // ---- staging source pointers (inverse-swizzled; dest is linear lane order) ----
  // slot s = wave*128 + q*64 + lane; r2=s>>3; p=s&7; pos=p^(r2&7);
  // row = 2*r2 + (pos>>2); chunk c = pos&3 (8 halves each).
  const _Float16* aSrc[2];
  const _Float16* bSrc[2];
#pragma unroll
  for (int q = 0; q < 2; q++) {
    const int sl = wave * 128 + q * 64 + lane;
    const int r2 = sl >> 3, p = sl & 7;
    const int pos = p ^ (r2 & 7);
    const int r = 2 * r2 + (pos >> 2);
    const int c = pos & 3;
    aSrc[q] = Xh + ((size_t)b * Tc + itmp[r]) * Ic + c * 8;
    bSrc[q] = WT + ((size_t)e * Jc + j0 + r) * Ic + c * 8;
  }
  const int wdst = wave * 2048;  // wave-uniform LDS dest base within a unit
  __syncthreads();               // all rowid reads done before staging overwrites

  // ---- swizzled ds_read byte offsets within a unit ----
  int offA[8], offB[4];
#pragma unroll
  for (int mi = 0; mi < 8; mi++) {
    const int R = wmb + mi * 16 + tr;
    const int r2 = R >> 1;
    offA[mi] = r2 * 128 + ((((R & 1) << 2) | quad) ^ (r2 & 7)) * 16;
  }
#pragma unroll
  for (int ni = 0; ni < 4; ni++) {
    const int R = wnb + ni * 16 + tr;
    const int r2 = R >> 1;
    offB[ni] = r2 * 128 + ((((R & 1) << 2) | quad) ^ (r2 & 7)) * 16;
  }

  floatx4 acc[8][4];
#pragma unroll
  for (int mi = 0; mi < 8; mi++)
#pragma unroll
    for (int ni = 0; ni < 4; ni++) acc[mi][ni] = {0.f, 0.f, 0.f, 0.f};

#define STAGE_A(U, SL) do { \
    char* d_ = smemc + (SL) * UNIT + wdst; \
    async16(aSrc[0] + (U) * 32, d_); \
    async16(aSrc[1] + (U) * 32, d_ + 1024); \
  } while (0)
#define STAGE_B(U, SL) do { \
    char* d_ = smemc + A_RING + (SL) * UNIT + wdst; \
    async16(bSrc[0] + (U) * 32, d_); \
    async16(bSrc[1] + (U) * 32, d_ + 1024); \
  } while (0)

  // phase: 12 ds_read_b128 -> stage B(u+1), A(u+2) -> barrier -> lgkmcnt(0)
  // (+rule-18 sched_barrier) -> setprio(1) -> 32 MFMA -> setprio(0) -> CLOSE
  // (counted vmcnt) -> barrier
#define PHASE(ASL, BSL, DOB, DOA, CLOSE) do { \
    const char* Ab_ = smemc + (ASL) * UNIT; \
    const char* Bb_ = smemc + A_RING + (BSL) * UNIT; \
    half8 af_[8], bf_[4]; \
    _Pragma("unroll") \
    for (int mi_ = 0; mi_ < 8; mi_++) af_[mi_] = *(const half8*)(Ab_ + offA[mi_]); \
    _Pragma("unroll") \
    for (int ni_ = 0; ni_ < 4; ni_++) bf_[ni_] = *(const half8*)(Bb_ + offB[ni_]); \
    DOB; DOA; \
    __builtin_amdgcn_s_barrier(); \
    asm volatile("s_waitcnt lgkmcnt(0)" ::: "memory"); \
    __builtin_amdgcn_sched_barrier(0); \
    __builtin_amdgcn_s_setprio(1); \
    _Pragma("unroll") \
    for (int mi_ = 0; mi_ < 8; mi_++) \
      _Pragma("unroll") \
      for (int ni_ = 0; ni_ < 4; ni_++) \
        acc[mi_][ni_] = __builtin_amdgcn_mfma_f32_16x16x32_f16( \
            af_[mi_], bf_[ni_], acc[mi_][ni_], 0, 0, 0); \
    __builtin_amdgcn_s_setprio(0); \
    CLOSE; \
    __builtin_amdgcn_s_barrier(); \
  } while (0)

  // ---- prologue: A(0),B(0) landed; A(1) left in flight (issued last)
  STAGE_A(0, 0); STAGE_B(0, 0); STAGE_A(1, 1);
  asm volatile("s_waitcnt vmcnt(2)" ::: "memory");
  __builtin_amdgcn_s_barrier();

  // ---- main loop: 30 phases (u = 0..29), unroll 6 so ring slots are static.
  // Steady state at phase-u start: A(u),B(u) landed; A(u+1) in flight.
  // Phase u issues B(u+1) then A(u+2); vmcnt(2) drains A(u+1),B(u+1),
  // leaves A(u+2). Counted, never 0.
  for (int u0 = 0; u0 < 30; u0 += 6) {
#pragma unroll
    for (int i = 0; i < 6; i++) {
      const int u = u0 + i;
      PHASE(i % 3, i & 1,
            STAGE_B(u + 1, (i + 1) & 1),
            STAGE_A(u + 2, (i + 2) % 3),
            asm volatile("s_waitcnt vmcnt(2)" ::: "memory"));
    }
  }
  // ---- u = 30: stage B(31) only; drain fully (the single vmcnt(0))
  PHASE(0, 0, STAGE_B(31, 1), (void)0,
        asm volatile("s_waitcnt vmcnt(0)" ::: "memory"));
  // ---- u = 31: compute only
  PHASE(1, 1, (void)0, (void)0, (void)0);
  __syncthreads();  // all LDS reads done before lbuf epilogue reuse
#undef PHASE
#undef STAGE_B
#undef STAGE_A

  // ---- epilogue: 8 passes of 32 rows x 256 cols through LDS, full-line stores
  constexpr int LST = 257;  // lbuf row stride (floats): pad breaks quad conflicts
  float* Yb = Y + (size_t)be * Kc * Jc;
#pragma unroll
  for (int pass = 0; pass < 8; pass++) {
    if ((wave >> 2) == (pass >> 2)) {
#pragma unroll
      for (int h = 0; h < 2; h++) {
        const int mi = (pass & 3) * 2 + h;
        const int rr = h * 16 + quad * 4;
#pragma unroll
        for (int ni = 0; ni < 4; ni++) {
          const int col = wnb + ni * 16 + tr;
#pragma unroll
          for (int r = 0; r < 4; r++)
            lbuf[(rr + r) * LST + col] = acc[mi][ni][r];
        }
      }
    }
    __syncthreads();
#pragma unroll
    for (int it = 0; it < 4; it++) {
      const int idx = tid + it * NT;
      const int rr = idx >> 6, c4 = idx & 63;
      floatx4 v = *(const floatx4*)&lbuf[rr * LST + c4 * 4];
      *(floatx4*)&Yb[(size_t)(k0 + pass * 32 + rr) * Jc + j0 + c4 * 4] = v;
    }
    __syncthreads();
  }
}

extern "C" void kernel_launch(void* const* d_in, const int* in_sizes, int n_in,
                              void* d_out, int out_size, void* d_ws, size_t ws_size,
                              hipStream_t stream) {
  const float* X = (const float*)d_in[0];
  const int* ind = (const int*)d_in[1];
  const float* W = (const float*)d_in[2];
  float* Y = (float*)d_out;

  const size_t nx = (size_t)Bc * Tc * Ic;
  _Float16* Xh = (_Float16*)d_ws;
  _Float16* WT = Xh + nx;

  cvt_kernel<<<Ec * 256 + 2048, 256, 0, stream>>>(X, Xh, (int)(nx / 8), W, WT);
  const int gemm_grid = (Bc * Ec) * (Kc / BM) * (Jc / BN);  // 512
  gemm_kernel<<<gemm_grid, NT, 0, stream>>>(ind, Xh, WT, Y);
}

// Round 5
// 307.482 us; speedup vs baseline: 3.4393x; 3.4393x over previous
//
#include <hip/hip_runtime.h>
#include <cstdint>
#include <cstddef>

// ExpertGather: Y[b,e,k,j] = sum_i X[b, ind[b,e,k], i] * W[e,i,j]
// B=4 T=4096 I=1024 E=16 K=512 J=1024
// Round 8 = Round 7 with the staging-index bug fixed.
//  - LESSON r7: STAGE_*(U,SL) offsets by U*32 where U is the GLOBAL K-HALF
//    index (0..31); r7 passed tile indices and its prologue staged half 0
//    into two slots then overwrote slot 0 => wrong K-slices => fail.
//    This round: STAGE takes half index u; TILE(T) stages u=2T+3 -> slot
//    (S0+3)&3 and u=2T+4 -> slot S0; prologue stages u=0,1,2 -> slots 0,1,2.
//    vmcnt ledger (audited): tile start = {2T,2T+1 landed; 2T+2 in flight
//    (4 loads)}; +8 loads per tile; vmcnt(4) leaves half 2T+4 in flight.
//    Single vmcnt(0) at T=14; T=15 compute-only.
//  - THEORY (r7, untested): compiler-visible LDS reads + "memory"-clobber
//    waitcnts let hipcc insert conservative per-phase vmcnt drains (can't
//    prove ds_reads don't alias in-flight global_load_lds) => counted-vmcnt
//    silently became drain-to-0 (m218-V1 penalty). Fix: inline-asm
//    ds_read_b128 on AS3 pointers, slot via literal offset: immediate
//    (if constexpr dispatch — no "n" formatting risk), bare waitcnt asms,
//    rule-18 sched_barrier(0) after lgkmcnt(0) and at MFMA-cluster end.
//  - LESSON r6: this tile needs ~224 VGPR/wave: launch_bounds(512,2) only;
//    (512,4) spills acc to scratch (FETCH 1.5GB, 8x slower).
//  - bf register-reuse across same-K-half phases: 24 b128/tile (floor).
//  - Ring 4x16KB/operand (128KB), epilogue + XCD swizzle: verbatim r4.

typedef float    floatx4 __attribute__((ext_vector_type(4)));
typedef _Float16 half8   __attribute__((ext_vector_type(8)));
typedef const __attribute__((address_space(3))) uint8_t* lds8_t;

constexpr int Bc = 4, Tc = 4096, Ic = 1024, Ec = 16, Kc = 512, Jc = 1024;
constexpr int BM = 256, BN = 256, NT = 512;
constexpr int UNIT = 16384;    // one K-half unit: 256 rows x 32 halves x 2B
constexpr int BOFF = 4 * UNIT; // B-region byte offset in smem

__device__ __forceinline__ void async16(const void* g, void* l) {
  __builtin_amdgcn_global_load_lds(
      (const __attribute__((address_space(1))) uint32_t*)g,
      (__attribute__((address_space(3))) uint32_t*)l, 16, 0, 0);
}

// ds_read_b128 from ring slot SLOT (0..3); base addr covers slot 0, slot
// selected by literal offset: immediate (UNIT=16384 apart).
template <int SLOT>
__device__ __forceinline__ half8 dsr128(lds8_t p) {
  half8 d;
  if constexpr (SLOT == 0)
    asm volatile("ds_read_b128 %0, %1 offset:0" : "=v"(d) : "v"(p));
  else if constexpr (SLOT == 1)
    asm volatile("ds_read_b128 %0, %1 offset:16384" : "=v"(d) : "v"(p));
  else if constexpr (SLOT == 2)
    asm volatile("ds_read_b128 %0, %1 offset:32768" : "=v"(d) : "v"(p));
  else
    asm volatile("ds_read_b128 %0, %1 offset:49152" : "=v"(d) : "v"(p));
  return d;
}

// ---------- fused pre-pass: W transpose->fp16 (blocks 0..4095), X->fp16 (rest) ----------
__global__ void cvt_kernel(const float* __restrict__ X, _Float16* __restrict__ Xh, int n8,
                           const float* __restrict__ W, _Float16* __restrict__ WT) {
  __shared__ float tile[64][65];
  const int bidx = blockIdx.x;
  if (bidx >= Ec * 256) {
    int i = (bidx - Ec * 256) * blockDim.x + threadIdx.x;
    const int stride = 2048 * blockDim.x;
    for (; i < n8; i += stride) {
      floatx4 v0 = ((const floatx4*)X)[2 * i];
      floatx4 v1 = ((const floatx4*)X)[2 * i + 1];
      half8 h;
      h[0] = (_Float16)v0.x; h[1] = (_Float16)v0.y; h[2] = (_Float16)v0.z; h[3] = (_Float16)v0.w;
      h[4] = (_Float16)v1.x; h[5] = (_Float16)v1.y; h[6] = (_Float16)v1.z; h[7] = (_Float16)v1.w;
      ((half8*)Xh)[i] = h;
    }
    return;
  }
  const int bid = bidx;
  const int e  = bid >> 8;
  const int i0 = ((bid >> 4) & 15) * 64;
  const int j0 = (bid & 15) * 64;
  const int tid = threadIdx.x;
  const int r  = tid >> 4;
  const int c4 = tid & 15;
  const float* src = W + ((size_t)e << 20) + (size_t)i0 * Jc + j0;
#pragma unroll
  for (int s = 0; s < 4; s++) {
    int rr = r + s * 16;
    floatx4 v = *(const floatx4*)(src + (size_t)rr * Jc + c4 * 4);
    tile[rr][c4 * 4 + 0] = v.x; tile[rr][c4 * 4 + 1] = v.y;
    tile[rr][c4 * 4 + 2] = v.z; tile[rr][c4 * 4 + 3] = v.w;
  }
  __syncthreads();
  const int jj = tid >> 2;
  const int ig = tid & 3;
  half8 hv0, hv1;
#pragma unroll
  for (int q = 0; q < 8; q++) hv0[q] = (_Float16)tile[ig * 16 + q][jj];
#pragma unroll
  for (int q = 0; q < 8; q++) hv1[q] = (_Float16)tile[ig * 16 + 8 + q][jj];
  _Float16* dst = WT + ((size_t)e << 20) + (size_t)(j0 + jj) * Ic + i0 + ig * 16;
  ((half8*)dst)[0] = hv0;
  ((half8*)dst)[1] = hv1;
}

// ---------- main grouped GEMM ----------
// Grid 512 = 8 chunks x 8 sharers x 8 XCD-slots (unchanged, verified).
// MFMA layouts (m89-verified): A/B m(n)=lane&15, k=(lane>>4)*8+j;
// C/D col=lane&15, row=(lane>>4)*4+reg.
__global__ __launch_bounds__(NT, 2) void gemm_kernel(
    const int* __restrict__ ind32,
    const _Float16* __restrict__ Xh, const _Float16* __restrict__ WT,
    float* __restrict__ Y) {
  __shared__ alignas(16) unsigned char smem[8 * UNIT];  // 128 KB ring
  char* smemc = (char*)smem;
  int* itmp = (int*)smem;      // rowid[0..255], is64 flag at [256] (pre-loop alias)
  float* lbuf = (float*)smem;  // epilogue reuse (32x257 floats fits)

  const int tid = threadIdx.x;
  const int bid = blockIdx.x;
  const int x = bid & 7, s = (bid >> 3) & 7, chunk = bid >> 6;
  const int g = chunk * 8 + x;       // 0..63 B-tile group
  const int e = g >> 2, nt = g & 3;  // expert, j-tile
  const int b = s >> 1, mt = s & 1;  // batch, k-tile
  const int be = b * Ec + e;
  const int k0 = mt * BM;
  const int j0 = nt * BN;

  // index dtype probe (int64 vs int32 storage), wave-parallel
  if (tid < 64) {
    int v = ind32[2 * tid + 1];
    unsigned long long m = __ballot(v != 0);
    if (tid == 0) itmp[256] = (m == 0ULL) ? 1 : 0;
  }
  __syncthreads();
  const int is64 = itmp[256];
  if (tid < BM) {
    int idx = be * Kc + k0 + tid;
    itmp[tid] = is64 ? ind32[2 * idx] : ind32[idx];
  }
  __syncthreads();

  const int lane = tid & 63;
  const int wave = tid >> 6;           // 0..7
  const int wmb = (wave >> 2) * 128;   // wave m base (2 rows of waves)
  const int wnb = (wave & 3) * 64;     // wave n base (4 cols of waves)
  const int quad = lane >> 4;
  const int tr = lane & 15;

  // ---- staging source pointers (inverse-swizzled; dest is linear lane order) ----
  // slot s = wave*128 + q*64 + lane; r2=s>>3; p=s&7; pos=p^(r2&7);
  // row = 2*r2 + (pos>>2); chunk c = pos&3 (8 halves each).
  const _Float16* aSrc[2];
  const _Float16* bSrc[2];
#pragma unroll
  for (int q = 0; q < 2; q++) {
    const int sl = wave * 128 + q * 64 + lane;
    const int r2 = sl >> 3, p = sl & 7;
    const int pos = p ^ (r2 & 7);
    const int r = 2 * r2 + (pos >> 2);
    const int c = pos & 3;
    aSrc[q] = Xh + ((size_t)b * Tc + itmp[r]) * Ic + c * 8;
    bSrc[q] = WT + ((size_t)e * Jc + j0 + r) * Ic + c * 8;
  }
  const int wdst = wave * 2048;  // wave-uniform LDS dest base within a unit
  __syncthreads();               // all rowid reads done before staging overwrites

  // ---- swizzled ds_read addresses (AS3, slot-0 base; slot via offset: imm) ----
  lds8_t aAddr[8];
  lds8_t bAddr[4];
#pragma unroll
  for (int mi = 0; mi < 8; mi++) {
    const int R = wmb + mi * 16 + tr;
    const int r2 = R >> 1;
    const int off = r2 * 128 + ((((R & 1) << 2) | quad) ^ (r2 & 7)) * 16;
    aAddr[mi] = (lds8_t)(smemc + off);
  }
#pragma unroll
  for (int ni = 0; ni < 4; ni++) {
    const int R = wnb + ni * 16 + tr;
    const int r2 = R >> 1;
    const int off = r2 * 128 + ((((R & 1) << 2) | quad) ^ (r2 & 7)) * 16;
    bAddr[ni] = (lds8_t)(smemc + BOFF + off);
  }

  floatx4 acc[8][4];
#pragma unroll
  for (int mi = 0; mi < 8; mi++)
#pragma unroll
    for (int ni = 0; ni < 4; ni++) acc[mi][ni] = {0.f, 0.f, 0.f, 0.f};

  // U = GLOBAL K-half index (0..31): source offset U*32 halves, dest slot SL.
#define STAGE_A(U, SL) do { \
    char* d_ = smemc + (SL) * UNIT + wdst; \
    async16(aSrc[0] + (U) * 32, d_); \
    async16(aSrc[1] + (U) * 32, d_ + 1024); \
  } while (0)
#define STAGE_B(U, SL) do { \
    char* d_ = smemc + BOFF + (SL) * UNIT + wdst; \
    async16(bSrc[0] + (U) * 32, d_); \
    async16(bSrc[1] + (U) * 32, d_ + 1024); \
  } while (0)
#define RD_A(DST, MH, SLOT) do { \
    _Pragma("unroll") \
    for (int mi_ = 0; mi_ < 4; mi_++) \
      DST[mi_] = dsr128<(SLOT)>(aAddr[(MH) * 4 + mi_]); \
  } while (0)
#define RD_B(DST, SLOT) do { \
    _Pragma("unroll") \
    for (int ni_ = 0; ni_ < 4; ni_++) \
      DST[ni_] = dsr128<(SLOT)>(bAddr[ni_]); \
  } while (0)
#define MFMA16(MH, AF, BF) do { \
    _Pragma("unroll") \
    for (int mi_ = 0; mi_ < 4; mi_++) \
      _Pragma("unroll") \
      for (int ni_ = 0; ni_ < 4; ni_++) \
        acc[(MH) * 4 + mi_][ni_] = __builtin_amdgcn_mfma_f32_16x16x32_f16( \
            AF[mi_], BF[ni_], acc[(MH) * 4 + mi_][ni_], 0, 0, 0); \
  } while (0)
// m201 template order: reads+stage -> barrier -> bare lgkmcnt(0) -> rule-18
// sched_barrier -> setprio(1) -> MFMA -> setprio(0) -> pin -> [vmcnt] -> barrier
#define PH_MID() do { \
    __builtin_amdgcn_s_barrier(); \
    asm volatile("s_waitcnt lgkmcnt(0)"); \
    __builtin_amdgcn_sched_barrier(0); \
    __builtin_amdgcn_s_setprio(1); \
  } while (0)
#define PH_END() do { \
    __builtin_amdgcn_s_setprio(0); \
    __builtin_amdgcn_sched_barrier(0); \
    __builtin_amdgcn_s_barrier(); \
  } while (0)
#define PH_END_VM(N) do { \
    __builtin_amdgcn_s_setprio(0); \
    __builtin_amdgcn_sched_barrier(0); \
    asm volatile("s_waitcnt vmcnt(" #N ")"); \
    __builtin_amdgcn_s_barrier(); \
  } while (0)

  half8 af0[4], af1[4], bf[4];

  // Steady tile T (halves 2T,2T+1 in slots S0=(2T)&3, S1=S0+1; SN=(S0+3)&3):
  //  P1: rd af0,bf@S0; stage A half(2T+3)->SN | mfma mh0
  //  P2: rd af1@S0;    stage B half(2T+3)->SN | mfma mh1   (bf reused)
  //  P3: rd af0,bf@S1; stage A half(2T+4)->S0 | mfma mh0   (S0 readers done @P2 bar)
  //  P4: rd af1@S1;    stage B half(2T+4)->S0 | mfma mh1; vmcnt(4)
  // Ledger: tile start = 4 loads in flight (half 2T+2); +8 during tile;
  // vmcnt(4) drains halves 2T+2,2T+3, leaves half 2T+4 (counted, never 0).
#define TILE(S0, S1, SN, T) do { \
    RD_A(af0, 0, S0); RD_B(bf, S0); STAGE_A(2 * (T) + 3, SN); \
    PH_MID(); MFMA16(0, af0, bf); PH_END(); \
    RD_A(af1, 1, S0); STAGE_B(2 * (T) + 3, SN); \
    PH_MID(); MFMA16(1, af1, bf); PH_END(); \
    RD_A(af0, 0, S1); RD_B(bf, S1); STAGE_A(2 * (T) + 4, S0); \
    PH_MID(); MFMA16(0, af0, bf); PH_END(); \
    RD_A(af1, 1, S1); STAGE_B(2 * (T) + 4, S0); \
    PH_MID(); MFMA16(1, af1, bf); PH_END_VM(4); \
  } while (0)

  // ---- prologue: halves 0,1,2 -> slots 0,1,2; vmcnt(4) => 0,1 landed, 2 in flight
  STAGE_A(0, 0); STAGE_B(0, 0);
  STAGE_A(1, 1); STAGE_B(1, 1);
  STAGE_A(2, 2); STAGE_B(2, 2);
  asm volatile("s_waitcnt vmcnt(4)");
  __builtin_amdgcn_s_barrier();

  // ---- main loop: T = 0..13 (slot sets alternate {0,1}/{2,3})
  for (int tp = 0; tp < 7; tp++) {
    const int t = 2 * tp;
    TILE(0, 1, 3, t);
    TILE(2, 3, 1, t + 1);
  }
  // ---- T = 14 (halves 28,29 @ slots 0,1): stage half 31 -> slot 3; vmcnt(0)
  RD_A(af0, 0, 0); RD_B(bf, 0); STAGE_A(31, 3);
  PH_MID(); MFMA16(0, af0, bf); PH_END();
  RD_A(af1, 1, 0); STAGE_B(31, 3);
  PH_MID(); MFMA16(1, af1, bf); PH_END();
  RD_A(af0, 0, 1); RD_B(bf, 1);
  PH_MID(); MFMA16(0, af0, bf); PH_END();
  RD_A(af1, 1, 1);
  PH_MID(); MFMA16(1, af1, bf); PH_END_VM(0);
  // ---- T = 15 (halves 30,31 @ slots 2,3): compute only
  RD_A(af0, 0, 2); RD_B(bf, 2);
  PH_MID(); MFMA16(0, af0, bf); PH_END();
  RD_A(af1, 1, 2);
  PH_MID(); MFMA16(1, af1, bf); PH_END();
  RD_A(af0, 0, 3); RD_B(bf, 3);
  PH_MID(); MFMA16(0, af0, bf); PH_END();
  RD_A(af1, 1, 3);
  PH_MID(); MFMA16(1, af1, bf);
  __builtin_amdgcn_s_setprio(0);
  __syncthreads();  // full drain before lbuf epilogue reuse
#undef TILE
#undef PH_END_VM
#undef PH_END
#undef PH_MID
#undef MFMA16
#undef RD_B
#undef RD_A
#undef STAGE_B
#undef STAGE_A

  // ---- epilogue: 8 passes of 32 rows x 256 cols through LDS, full-line stores
  constexpr int LST = 257;  // lbuf row stride (floats): pad breaks quad conflicts
  float* Yb = Y + (size_t)be * Kc * Jc;
#pragma unroll
  for (int pass = 0; pass < 8; pass++) {
    if ((wave >> 2) == (pass >> 2)) {
#pragma unroll
      for (int h = 0; h < 2; h++) {
        const int mi = (pass & 3) * 2 + h;
        const int rr = h * 16 + quad * 4;
#pragma unroll
        for (int ni = 0; ni < 4; ni++) {
          const int col = wnb + ni * 16 + tr;
#pragma unroll
          for (int r = 0; r < 4; r++)
            lbuf[(rr + r) * LST + col] = acc[mi][ni][r];
        }
      }
    }
    __syncthreads();
#pragma unroll
    for (int it = 0; it < 4; it++) {
      const int idx = tid + it * NT;
      const int rr = idx >> 6, c4 = idx & 63;
      floatx4 v = *(const floatx4*)&lbuf[rr * LST + c4 * 4];
      *(floatx4*)&Yb[(size_t)(k0 + pass * 32 + rr) * Jc + j0 + c4 * 4] = v;
    }
    __syncthreads();
  }
}

extern "C" void kernel_launch(void* const* d_in, const int* in_sizes, int n_in,
                              void* d_out, int out_size, void* d_ws, size_t ws_size,
                              hipStream_t stream) {
  const float* X = (const float*)d_in[0];
  const int* ind = (const int*)d_in[1];
  const float* W = (const float*)d_in[2];
  float* Y = (float*)d_out;

  const size_t nx = (size_t)Bc * Tc * Ic;
  _Float16* Xh = (_Float16*)d_ws;
  _Float16* WT = Xh + nx;

  cvt_kernel<<<Ec * 256 + 2048, 256, 0, stream>>>(X, Xh, (int)(nx / 8), W, WT);
  const int gemm_grid = (Bc * Ec) * (Kc / BM) * (Jc / BN);  // 512
  gemm_kernel<<<gemm_grid, NT, 0, stream>>>(ind, Xh, WT, Y);
}